// Round 1
// baseline (1874.354 us; speedup 1.0000x reference)
//
#include <hip/hip_runtime.h>
#include <cmath>

#define TT 16
#define BB 16
#define NN 1024
#define EE 16384
#define FIN 128
#define MIDC 16
#define HH 256
#define KK 820
#define HS 17   // padded LDS row stride (17 floats) -> bank-conflict-free scatter

// dynamic LDS layout (floats): hbuf[NN*HS] abuf[NN*HS] sc[NN] dinv[NN] ub[NN] hist[256] ctrl[16] embacc[256]
#define SM_FLOATS (NN*HS*2 + NN*3 + 256 + 16 + 256)
#define SM_BYTES  (SM_FLOATS * 4)

// ---------------------------------------------------------------------------
// K1: per-graph pipeline: GCN1+relu -> SAG score -> top-K (radix select) ->
//     gate -> GCN2 (aggregate in 16-dim, matmul 16x256 fused w/ mean pool)
// one block per graph, 1024 threads (= N nodes)
// ---------------------------------------------------------------------------
__global__ __launch_bounds__(1024) void k_graph(
    const float* __restrict__ x, const int* __restrict__ ei,
    const float* __restrict__ W1, const float* __restrict__ b1,
    const float* __restrict__ Wl, const float* __restrict__ Wr,
    const float* __restrict__ bsag, const float* __restrict__ W2,
    const float* __restrict__ b2, float* __restrict__ emb)
{
  extern __shared__ float sm[];
  float*    hbuf = sm;                          // [NN][HS]
  float*    abuf = sm + NN*HS;                  // [NN][HS]
  float*    sc   = abuf + NN*HS;                // [NN]
  float*    dinv = sc + NN;                     // [NN] (also deg accumulator)
  unsigned* ub   = (unsigned*)(dinv + NN);      // [NN] keys, later kept-mask
  int*      hist = (int*)(ub + NN);             // [256]
  int*      ctrl = hist + 256;                  // [16]
  float*    embacc = (float*)(ctrl + 16);       // [256]

  const int g   = blockIdx.x;
  const int tid = threadIdx.x;
  const float* xg   = x  + (size_t)g * (NN*FIN);
  const int*   srcp = ei + (size_t)g * (2*EE);
  const int*   dstp = srcp + EE;

  // ---- init ----
  for (int i = tid; i < NN*HS; i += 1024) abuf[i] = 0.0f;
  dinv[tid] = 1.0f;                    // deg starts at 1 (self-loop weight)
  if (tid < HH) embacc[tid] = 0.0f;
  __syncthreads();

  // ---- conv1 matmul: h = x @ W1 -> hbuf (thread = node) ----
  {
    const float4* xr = (const float4*)(xg + (size_t)tid * FIN);
    float acc[MIDC];
#pragma unroll
    for (int c = 0; c < MIDC; ++c) acc[c] = 0.0f;
    for (int k4 = 0; k4 < FIN/4; ++k4) {
      float4 v = xr[k4];
      float xv[4] = {v.x, v.y, v.z, v.w};
#pragma unroll
      for (int j = 0; j < 4; ++j) {
        const float* wrow = W1 + (k4*4 + j)*MIDC;   // wave-uniform -> s_load
#pragma unroll
        for (int c = 0; c < MIDC; ++c) acc[c] = fmaf(xv[j], wrow[c], acc[c]);
      }
    }
#pragma unroll
    for (int c = 0; c < MIDC; ++c) hbuf[tid*HS + c] = acc[c];
  }

  // ---- conv1 degree ----
  for (int e = tid; e < EE; e += 1024) atomicAdd(&dinv[dstp[e]], 1.0f);
  __syncthreads();
  dinv[tid] = rsqrtf(dinv[tid]);
  __syncthreads();

  // ---- conv1 aggregate: abuf[d][c] += h[s][c] * dinv[s]*dinv[d] ----
  {
    const int c = tid & 15;
    for (int e = (tid >> 4); e < EE; e += 64) {
      int s = srcp[e], d = dstp[e];
      float coef = dinv[s] * dinv[d];
      atomicAdd(&abuf[d*HS + c], hbuf[s*HS + c] * coef);
    }
  }
  __syncthreads();

  // ---- h1 = relu(agg + h*dinv^2 + b1) -> hbuf ----
  for (int i = tid; i < NN*MIDC; i += 1024) {
    int node = i >> 4, c = i & 15;
    float di = dinv[node];
    float v = abuf[node*HS + c] + hbuf[node*HS + c] * di * di + b1[c];
    hbuf[node*HS + c] = fmaxf(v, 0.0f);
  }
  __syncthreads();
  for (int i = tid; i < NN*HS; i += 1024) abuf[i] = 0.0f;
  __syncthreads();

  // ---- SAG aggregate: abuf[d][c] += h1[s][c] ----
  {
    const int c = tid & 15;
    for (int e = (tid >> 4); e < EE; e += 64) {
      int s = srcp[e], d = dstp[e];
      atomicAdd(&abuf[d*HS + c], hbuf[s*HS + c]);
    }
  }
  __syncthreads();

  // ---- score + order-preserving uint key ----
  {
    float a = bsag[0];
#pragma unroll
    for (int c = 0; c < MIDC; ++c)
      a += abuf[tid*HS + c]*Wl[c] + hbuf[tid*HS + c]*Wr[c];
    sc[tid] = a;
    unsigned ubits = __float_as_uint(a);
    ubits = (ubits & 0x80000000u) ? ~ubits : (ubits | 0x80000000u);
    ub[tid] = ubits;
  }
  __syncthreads();

  // ---- radix select: find K-th largest key (exact) ----
  unsigned myu = ub[tid];
  int remK = KK;
  unsigned pref = 0;
  for (int byte = 3; byte >= 0; --byte) {
    if (tid < 256) hist[tid] = 0;
    __syncthreads();
    const int sh = byte * 8;
    const unsigned hi_mask = (byte == 3) ? 0u : (0xFFFFFFFFu << (sh + 8));
    if ((myu & hi_mask) == pref) atomicAdd(&hist[(myu >> sh) & 255u], 1);
    __syncthreads();
    if (tid == 0) {
      int cum = 0, b = 255;
      for (; b > 0; --b) { if (cum + hist[b] >= remK) break; cum += hist[b]; }
      ctrl[0] = remK - cum;
      ctrl[1] = b;
    }
    __syncthreads();
    remK = ctrl[0];
    pref |= ((unsigned)ctrl[1]) << sh;
    __syncthreads();
  }
  const unsigned vstar = pref;   // K-th largest key
  const int need = remK;         // ties at vstar to keep (lowest indices first)

  int kept;
  if (myu > vstar) kept = 1;
  else if (myu == vstar) {
    int tr = 0;
    for (int j = 0; j < tid; ++j) tr += (ub[j] == vstar) ? 1 : 0;
    kept = (tr < need) ? 1 : 0;
  } else kept = 0;
  float gate = tanhf(sc[tid]);
  __syncthreads();               // all tie scans done before ub reuse

  ub[tid]   = (unsigned)kept;    // ub now = kept mask
  dinv[tid] = 1.0f;              // reset as deg2 accumulator
  {
    float gk = kept ? gate : 0.0f;
#pragma unroll
    for (int c = 0; c < MIDC; ++c) hbuf[tid*HS + c] *= gk;   // xp
  }
  __syncthreads();
  for (int i = tid; i < NN*HS; i += 1024) abuf[i] = 0.0f;
  __syncthreads();

  // ---- conv2 degree (valid edges = both endpoints kept) ----
  for (int e = tid; e < EE; e += 1024) {
    int s = srcp[e], d = dstp[e];
    if (ub[s] && ub[d]) atomicAdd(&dinv[d], 1.0f);
  }
  __syncthreads();
  dinv[tid] = rsqrtf(dinv[tid]);
  __syncthreads();

  // ---- conv2 aggregate in 16-dim (W2 pulled out by linearity) ----
  {
    const int c = tid & 15;
    for (int e = (tid >> 4); e < EE; e += 64) {
      int s = srcp[e], d = dstp[e];
      if (ub[s] && ub[d]) {
        float coef = dinv[s] * dinv[d];
        atomicAdd(&abuf[d*HS + c], hbuf[s*HS + c] * coef);
      }
    }
  }
  __syncthreads();

  // ---- pre2 = agg + xp*dinv^2 -> hbuf ----
  for (int i = tid; i < NN*MIDC; i += 1024) {
    int node = i >> 4, c = i & 15;
    float di = dinv[node];
    hbuf[node*HS + c] = abuf[node*HS + c] + hbuf[node*HS + c]*di*di;
  }
  __syncthreads();

  // ---- out2 = relu(pre2 @ W2 + b2); mean pool over kept nodes ----
  {
    const int h = tid & 255;                 // thread's fixed output channel
    float part = 0.0f;
    for (int i = (tid >> 8); i < NN; i += 4) {   // i wave-uniform
      if (!ub[i]) continue;
      float a = b2[h];
#pragma unroll
      for (int c = 0; c < MIDC; ++c) a = fmaf(hbuf[i*HS + c], W2[c*HH + h], a);
      part += fmaxf(a, 0.0f);
    }
    atomicAdd(&embacc[h], part);
  }
  __syncthreads();
  if (tid < HH) emb[(size_t)g*HH + tid] = embacc[tid] * (1.0f/(float)KK);
}

// ---------------------------------------------------------------------------
// K2: A[t,b,j] = emb[t,b]@W_ih^T + b_ih + b_hh   (t-independent LSTM input part)
// one block per (t,b), 256 threads, 4 gate rows each (j = tid + 256*q)
// ---------------------------------------------------------------------------
__global__ __launch_bounds__(256) void k_gatepre(
    const float* __restrict__ emb, const float* __restrict__ W_ih,
    const float* __restrict__ b_ih, const float* __restrict__ b_hh,
    float* __restrict__ A)
{
  __shared__ __align__(16) float es[HH];
  const int g = blockIdx.x, tid = threadIdx.x;
  es[tid] = emb[(size_t)g*HH + tid];
  __syncthreads();
  const float4* w0 = (const float4*)(W_ih + (size_t)(tid      )*HH);
  const float4* w1 = (const float4*)(W_ih + (size_t)(tid + 256)*HH);
  const float4* w2 = (const float4*)(W_ih + (size_t)(tid + 512)*HH);
  const float4* w3 = (const float4*)(W_ih + (size_t)(tid + 768)*HH);
  const float4* e4p = (const float4*)es;
  float a0 = 0, a1 = 0, a2 = 0, a3 = 0;
  for (int k4 = 0; k4 < HH/4; ++k4) {
    float4 e4 = e4p[k4];
    float4 w;
    w = w0[k4]; a0 += e4.x*w.x + e4.y*w.y + e4.z*w.z + e4.w*w.w;
    w = w1[k4]; a1 += e4.x*w.x + e4.y*w.y + e4.z*w.z + e4.w*w.w;
    w = w2[k4]; a2 += e4.x*w.x + e4.y*w.y + e4.z*w.z + e4.w*w.w;
    w = w3[k4]; a3 += e4.x*w.x + e4.y*w.y + e4.z*w.z + e4.w*w.w;
  }
  float* Ag = A + (size_t)g*1024;
  Ag[tid      ] = a0 + b_ih[tid      ] + b_hh[tid      ];
  Ag[tid + 256] = a1 + b_ih[tid + 256] + b_hh[tid + 256];
  Ag[tid + 512] = a2 + b_ih[tid + 512] + b_hh[tid + 512];
  Ag[tid + 768] = a3 + b_ih[tid + 768] + b_hh[tid + 768];
}

// ---------------------------------------------------------------------------
// K3: recurrent LSTM (batch-parallel: one block per b) + classifier
// thread tid owns hidden unit tid: computes gates i,f,g,o; c in register
// ---------------------------------------------------------------------------
__global__ __launch_bounds__(256) void k_lstm(
    const float* __restrict__ A, const float* __restrict__ W_hh,
    const float* __restrict__ cls_W, const float* __restrict__ cls_b,
    float* __restrict__ out)
{
  __shared__ __align__(16) float hs[HH];
  __shared__ float wsum[4];
  const int b = blockIdx.x, tid = threadIdx.x;
  hs[tid] = 0.0f;
  float c = 0.0f;
  const float4* wi = (const float4*)(W_hh + (size_t)(tid      )*HH);
  const float4* wf = (const float4*)(W_hh + (size_t)(tid + 256)*HH);
  const float4* wg = (const float4*)(W_hh + (size_t)(tid + 512)*HH);
  const float4* wo = (const float4*)(W_hh + (size_t)(tid + 768)*HH);
  const float4* h4p = (const float4*)hs;
  __syncthreads();
  for (int t = 0; t < TT; ++t) {
    const float* At = A + ((size_t)t*BB + b)*1024;
    float gi = At[tid], gf = At[tid+256], gg = At[tid+512], go = At[tid+768];
    for (int k4 = 0; k4 < HH/4; ++k4) {
      float4 h4 = h4p[k4];
      float4 w;
      w = wi[k4]; gi += h4.x*w.x + h4.y*w.y + h4.z*w.z + h4.w*w.w;
      w = wf[k4]; gf += h4.x*w.x + h4.y*w.y + h4.z*w.z + h4.w*w.w;
      w = wg[k4]; gg += h4.x*w.x + h4.y*w.y + h4.z*w.z + h4.w*w.w;
      w = wo[k4]; go += h4.x*w.x + h4.y*w.y + h4.z*w.z + h4.w*w.w;
    }
    float iv = 1.0f/(1.0f + expf(-gi));
    float fv = 1.0f/(1.0f + expf(-gf));
    float gv = tanhf(gg);
    float ov = 1.0f/(1.0f + expf(-go));
    c = fv*c + iv*gv;
    float h = ov * tanhf(c);
    __syncthreads();          // all reads of previous hs complete
    hs[tid] = h;
    __syncthreads();
  }
  // classifier: out[b] = sum_k hs[k]*cls_W[k] + cls_b
  float p = hs[tid] * cls_W[tid];
#pragma unroll
  for (int off = 32; off >= 1; off >>= 1) p += __shfl_down(p, off);
  if ((tid & 63) == 0) wsum[tid >> 6] = p;
  __syncthreads();
  if (tid == 0) out[b] = wsum[0] + wsum[1] + wsum[2] + wsum[3] + cls_b[0];
}

// ---------------------------------------------------------------------------
extern "C" void kernel_launch(void* const* d_in, const int* in_sizes, int n_in,
                              void* d_out, int out_size, void* d_ws, size_t ws_size,
                              hipStream_t stream)
{
  const float* x    = (const float*)d_in[0];
  const int*   ei   = (const int*)  d_in[1];
  const float* W1   = (const float*)d_in[2];
  const float* b1   = (const float*)d_in[3];
  const float* Wl   = (const float*)d_in[4];
  const float* Wr   = (const float*)d_in[5];
  const float* bs   = (const float*)d_in[6];
  const float* W2   = (const float*)d_in[7];
  const float* b2   = (const float*)d_in[8];
  const float* Wih  = (const float*)d_in[9];
  const float* Whh  = (const float*)d_in[10];
  const float* bih  = (const float*)d_in[11];
  const float* bhh  = (const float*)d_in[12];
  const float* clsW = (const float*)d_in[13];
  const float* clsb = (const float*)d_in[14];
  float* out = (float*)d_out;

  float* emb = (float*)d_ws;                    // [T*B, 256]
  float* A   = emb + (size_t)TT*BB*HH;          // [T*B, 1024]

  (void)hipFuncSetAttribute(reinterpret_cast<const void*>(k_graph),
      hipFuncAttributeMaxDynamicSharedMemorySize, SM_BYTES);

  hipLaunchKernelGGL(k_graph, dim3(TT*BB), dim3(1024), SM_BYTES, stream,
                     x, ei, W1, b1, Wl, Wr, bs, W2, b2, emb);
  hipLaunchKernelGGL(k_gatepre, dim3(TT*BB), dim3(256), 0, stream,
                     emb, Wih, bih, bhh, A);
  hipLaunchKernelGGL(k_lstm, dim3(BB), dim3(256), 0, stream,
                     A, Whh, clsW, clsb, out);
}

// Round 3
// 423.210 us; speedup vs baseline: 4.4289x; 4.4289x over previous
//
#include <hip/hip_runtime.h>
#include <cmath>

#define TT 16
#define BB 16
#define NN 1024
#define EE 16384
#define FIN 128
#define MIDC 16
#define HH 256
#define KK 820
#define HS 20           // hbuf row stride in floats (80 B, 16 B aligned for ds_read_b128)

// ---- LDS float-slot layout for k_graph ----
#define OFF_HBUF   0
#define N_HBUF     (NN*HS)                    // 20480
#define OFF_CSR    (OFF_HBUF + N_HBUF)        // ushort[EE] -> 8192 float slots (reused as partials[16][256] at the end)
#define N_CSR      (EE/2)
#define OFF_HEAD   (OFF_CSR + N_CSR)          // int[NN+1]
#define OFF_CUR    (OFF_HEAD + NN + 1)        // int[NN]
#define OFF_SCANA  (OFF_CUR + NN)             // int[NN]
#define OFF_DINV   (OFF_SCANA + NN)           // float[NN] (aliases scanB during the prefix scan)
#define OFF_UB     (OFF_DINV + NN)            // uint[NN] kept mask
#define OFF_HIST   (OFF_UB + NN)              // int[256]
#define OFF_S      (OFF_HIST + 256)           // int[256] suffix sums
#define OFF_WCNT   (OFF_S + 256)              // int[16]
#define OFF_CTRL   (OFF_WCNT + 16)            // int[8]
#define SM_FLOATS  (OFF_CTRL + 8)
#define SM_BYTES   (SM_FLOATS * 4)            // ~137.3 KB

// ---------------------------------------------------------------------------
// K1: one block per graph, 1024 threads (= N nodes). conv1 -> CSR build ->
// gather conv1 -> gather SAG -> radix top-K -> gate -> gather conv2 ->
// 16x256 matmul + relu + mean pool.  No float atomics anywhere.
// (unchanged from round 2 — audited clean; round-2 failure was k_lstm)
// ---------------------------------------------------------------------------
__global__ __launch_bounds__(1024) void k_graph(
    const float* __restrict__ x, const int* __restrict__ ei,
    const float* __restrict__ W1, const float* __restrict__ b1,
    const float* __restrict__ Wl, const float* __restrict__ Wr,
    const float* __restrict__ bsag, const float* __restrict__ W2,
    const float* __restrict__ b2, float* __restrict__ emb)
{
  extern __shared__ __align__(16) float sm[];
  float*          hbuf  = sm + OFF_HBUF;
  float4*         hb4   = (float4*)hbuf;
  unsigned short* csr   = (unsigned short*)(sm + OFF_CSR);
  int*            head  = (int*)(sm + OFF_HEAD);
  int*            cur   = (int*)(sm + OFF_CUR);
  int*            scanA = (int*)(sm + OFF_SCANA);
  int*            scanB = (int*)(sm + OFF_DINV);     // alias, freed before dinv use
  float*          dinvb = sm + OFF_DINV;
  unsigned*       ubv   = (unsigned*)(sm + OFF_UB);
  int*            hist  = (int*)(sm + OFF_HIST);
  int*            S     = (int*)(sm + OFF_S);
  int*            wcnt  = (int*)(sm + OFF_WCNT);
  int*            ctrl  = (int*)(sm + OFF_CTRL);

  const int g   = blockIdx.x;
  const int tid = threadIdx.x;
  const float* xg   = x  + (size_t)g * (NN*FIN);
  const int*   srcp = ei + (size_t)g * (2*EE);
  const int*   dstp = srcp + EE;

  cur[tid] = 0;

  // ---- conv1 matmul: hown = x_row @ W1 (W1 via wave-uniform s_loads) ----
  float hown[MIDC];
  {
    const float4* xr = (const float4*)(xg + (size_t)tid * FIN);
#pragma unroll
    for (int c = 0; c < MIDC; ++c) hown[c] = 0.0f;
    for (int k4 = 0; k4 < FIN/4; ++k4) {
      float4 v = xr[k4];
      const float* w0 = W1 + (k4*4 + 0)*MIDC;
      const float* w1 = W1 + (k4*4 + 1)*MIDC;
      const float* w2 = W1 + (k4*4 + 2)*MIDC;
      const float* w3 = W1 + (k4*4 + 3)*MIDC;
#pragma unroll
      for (int c = 0; c < MIDC; ++c)
        hown[c] += v.x*w0[c] + v.y*w1[c] + v.z*w2[c] + v.w*w3[c];
    }
    hb4[tid*5+0] = make_float4(hown[0],  hown[1],  hown[2],  hown[3]);
    hb4[tid*5+1] = make_float4(hown[4],  hown[5],  hown[6],  hown[7]);
    hb4[tid*5+2] = make_float4(hown[8],  hown[9],  hown[10], hown[11]);
    hb4[tid*5+3] = make_float4(hown[12], hown[13], hown[14], hown[15]);
  }
  __syncthreads();

  // ---- degree count (int atomics, native) ----
  for (int e = tid; e < EE; e += 1024) atomicAdd(&cur[dstp[e]], 1);
  __syncthreads();

  // ---- exclusive prefix scan (Hillis-Steele, ping-pong) ----
  {
    int v = cur[tid];
    scanA[tid] = v;
    __syncthreads();
    int* s_ = scanA; int* d_ = scanB;
    for (int off = 1; off < NN; off <<= 1) {
      int t = s_[tid];
      if (tid >= off) t += s_[tid - off];
      d_[tid] = t;
      __syncthreads();
      int* tmp = s_; s_ = d_; d_ = tmp;
    }
    int inc = s_[tid];
    int ex  = inc - v;
    __syncthreads();                 // all scan reads done before dinvb overwrite
    head[tid] = ex;
    cur[tid]  = ex;
    if (tid == 0) head[NN] = EE;
    dinvb[tid] = rsqrtf((float)(v + 1));
  }
  __syncthreads();

  // ---- CSR fill (src ids as ushort) ----
  for (int e = tid; e < EE; e += 1024) {
    int s = srcp[e], d = dstp[e];
    int pos = atomicAdd(&cur[d], 1);
    csr[pos] = (unsigned short)s;
  }
  __syncthreads();

  const int beg = head[tid], end = head[tid+1];

  // ---- gather conv1: acc = sum_s dinv_s * h_s ----
  float h1own[MIDC];
  {
    float accv[MIDC];
#pragma unroll
    for (int c = 0; c < MIDC; ++c) accv[c] = 0.0f;
    for (int p = beg; p < end; ++p) {
      int s = csr[p];
      float ds_ = dinvb[s];
      float4 a0 = hb4[s*5+0], a1 = hb4[s*5+1], a2 = hb4[s*5+2], a3 = hb4[s*5+3];
      accv[0]  += a0.x*ds_; accv[1]  += a0.y*ds_; accv[2]  += a0.z*ds_; accv[3]  += a0.w*ds_;
      accv[4]  += a1.x*ds_; accv[5]  += a1.y*ds_; accv[6]  += a1.z*ds_; accv[7]  += a1.w*ds_;
      accv[8]  += a2.x*ds_; accv[9]  += a2.y*ds_; accv[10] += a2.z*ds_; accv[11] += a2.w*ds_;
      accv[12] += a3.x*ds_; accv[13] += a3.y*ds_; accv[14] += a3.z*ds_; accv[15] += a3.w*ds_;
    }
    float di = dinvb[tid];
#pragma unroll
    for (int c = 0; c < MIDC; ++c)
      h1own[c] = fmaxf(di*accv[c] + hown[c]*di*di + b1[c], 0.0f);
  }
  __syncthreads();
  hb4[tid*5+0] = make_float4(h1own[0],  h1own[1],  h1own[2],  h1own[3]);
  hb4[tid*5+1] = make_float4(h1own[4],  h1own[5],  h1own[6],  h1own[7]);
  hb4[tid*5+2] = make_float4(h1own[8],  h1own[9],  h1own[10], h1own[11]);
  hb4[tid*5+3] = make_float4(h1own[12], h1own[13], h1own[14], h1own[15]);
  __syncthreads();

  // ---- gather SAG: agg = sum_s h1_s ; score ----
  float score;
  unsigned myu;
  {
    float aggv[MIDC];
#pragma unroll
    for (int c = 0; c < MIDC; ++c) aggv[c] = 0.0f;
    for (int p = beg; p < end; ++p) {
      int s = csr[p];
      float4 a0 = hb4[s*5+0], a1 = hb4[s*5+1], a2 = hb4[s*5+2], a3 = hb4[s*5+3];
      aggv[0]  += a0.x; aggv[1]  += a0.y; aggv[2]  += a0.z; aggv[3]  += a0.w;
      aggv[4]  += a1.x; aggv[5]  += a1.y; aggv[6]  += a1.z; aggv[7]  += a1.w;
      aggv[8]  += a2.x; aggv[9]  += a2.y; aggv[10] += a2.z; aggv[11] += a2.w;
      aggv[12] += a3.x; aggv[13] += a3.y; aggv[14] += a3.z; aggv[15] += a3.w;
    }
    score = bsag[0];
#pragma unroll
    for (int c = 0; c < MIDC; ++c) score += aggv[c]*Wl[c] + h1own[c]*Wr[c];
    unsigned ubits = __float_as_uint(score);
    myu = (ubits & 0x80000000u) ? ~ubits : (ubits | 0x80000000u);
  }

  // ---- radix select K-th largest key (parallel suffix scan per round) ----
  int remK = KK;
  unsigned pref = 0;
  for (int byte = 3; byte >= 0; --byte) {
    if (tid < 256) hist[tid] = 0;
    __syncthreads();
    const int sh = byte * 8;
    const unsigned hi_mask = (byte == 3) ? 0u : (0xFFFFFFFFu << (sh + 8));
    if ((myu & hi_mask) == pref) atomicAdd(&hist[(myu >> sh) & 255u], 1);
    __syncthreads();
    if (tid < 64) {
      int h0 = hist[tid*4+0], h1_ = hist[tid*4+1], h2_ = hist[tid*4+2], h3_ = hist[tid*4+3];
      int s3 = h3_, s2 = h2_ + s3, s1 = h1_ + s2, s0 = h0 + s1;
      int run = s0;
#pragma unroll
      for (int off = 1; off < 64; off <<= 1) {
        int o = __shfl_down(run, off);
        if (tid + off < 64) run += o;
      }
      int above = run - s0;
      S[tid*4+0] = above + s0;
      S[tid*4+1] = above + s1;
      S[tid*4+2] = above + s2;
      S[tid*4+3] = above + s3;
    }
    __syncthreads();
    if (tid < 256) {
      int Sv = S[tid];
      int Sn = (tid < 255) ? S[tid+1] : 0;
      if (Sv >= remK && Sn < remK) { ctrl[0] = remK - Sn; ctrl[1] = tid; }
    }
    __syncthreads();
    remK  = ctrl[0];
    pref |= ((unsigned)ctrl[1]) << sh;
    __syncthreads();
  }
  const unsigned vstar = pref;
  const int need = remK;

  // ---- kept mask: ties broken by lowest index (ballot-based count) ----
  {
    const int wid = tid >> 6, lane = tid & 63;
    bool eq = (myu == vstar);
    unsigned long long m = __ballot(eq);
    if (lane == 0) wcnt[wid] = __popcll(m);
    __syncthreads();
    int before = (lane == 0) ? 0 : __popcll(m & ((~0ull) >> (64 - lane)));
    for (int w = 0; w < wid; ++w) before += wcnt[w];
    int kept = (myu > vstar) ? 1 : (eq ? (before < need) : 0);
    float gate = kept ? tanhf(score) : 0.0f;
#pragma unroll
    for (int c = 0; c < MIDC; ++c) h1own[c] *= gate;    // h1own becomes xp (0 if dropped)
    hb4[tid*5+0] = make_float4(h1own[0],  h1own[1],  h1own[2],  h1own[3]);
    hb4[tid*5+1] = make_float4(h1own[4],  h1own[5],  h1own[6],  h1own[7]);
    hb4[tid*5+2] = make_float4(h1own[8],  h1own[9],  h1own[10], h1own[11]);
    hb4[tid*5+3] = make_float4(h1own[12], h1own[13], h1own[14], h1own[15]);
    ubv[tid] = (unsigned)kept;
  }
  __syncthreads();

  // ---- conv2 degree over valid edges; dinv2 ----
  float di2;
  {
    int cnt2 = 0;
    for (int p = beg; p < end; ++p) cnt2 += (int)ubv[csr[p]];
    di2 = rsqrtf((float)(1 + cnt2));
    dinvb[tid] = di2;           // old dinv has no remaining readers
  }
  __syncthreads();

  // ---- gather conv2 (xp already zero for dropped sources) ----
  {
    float acc2[MIDC];
#pragma unroll
    for (int c = 0; c < MIDC; ++c) acc2[c] = 0.0f;
    for (int p = beg; p < end; ++p) {
      int s = csr[p];
      float ds_ = dinvb[s];
      float4 a0 = hb4[s*5+0], a1 = hb4[s*5+1], a2 = hb4[s*5+2], a3 = hb4[s*5+3];
      acc2[0]  += a0.x*ds_; acc2[1]  += a0.y*ds_; acc2[2]  += a0.z*ds_; acc2[3]  += a0.w*ds_;
      acc2[4]  += a1.x*ds_; acc2[5]  += a1.y*ds_; acc2[6]  += a1.z*ds_; acc2[7]  += a1.w*ds_;
      acc2[8]  += a2.x*ds_; acc2[9]  += a2.y*ds_; acc2[10] += a2.z*ds_; acc2[11] += a2.w*ds_;
      acc2[12] += a3.x*ds_; acc2[13] += a3.y*ds_; acc2[14] += a3.z*ds_; acc2[15] += a3.w*ds_;
    }
#pragma unroll
    for (int c = 0; c < MIDC; ++c)
      h1own[c] = di2*acc2[c] + h1own[c]*di2*di2;        // pre2
  }
  __syncthreads();
  hb4[tid*5+0] = make_float4(h1own[0],  h1own[1],  h1own[2],  h1own[3]);
  hb4[tid*5+1] = make_float4(h1own[4],  h1own[5],  h1own[6],  h1own[7]);
  hb4[tid*5+2] = make_float4(h1own[8],  h1own[9],  h1own[10], h1own[11]);
  hb4[tid*5+3] = make_float4(h1own[12], h1own[13], h1own[14], h1own[15]);
  __syncthreads();

  // ---- out2 = relu(pre2 @ W2 + b2); mean pool over kept nodes ----
  {
    const int ig = tid >> 6, h4 = tid & 63;
    float4 w2c[MIDC];
#pragma unroll
    for (int c = 0; c < MIDC; ++c) w2c[c] = *(const float4*)(W2 + c*HH + (h4 << 2));
    float4 bv = *(const float4*)(b2 + (h4 << 2));
    float4 pacc = make_float4(0.f, 0.f, 0.f, 0.f);
    for (int k = 0; k < 64; ++k) {
      int i = (ig << 6) + k;                 // wave-uniform -> LDS broadcasts
      if (ubv[i] == 0u) continue;
      float4 v0 = hb4[i*5+0], v1 = hb4[i*5+1], v2 = hb4[i*5+2], v3 = hb4[i*5+3];
      float vv[MIDC] = {v0.x,v0.y,v0.z,v0.w, v1.x,v1.y,v1.z,v1.w,
                        v2.x,v2.y,v2.z,v2.w, v3.x,v3.y,v3.z,v3.w};
      float t0 = bv.x, t1 = bv.y, t2 = bv.z, t3 = bv.w;
#pragma unroll
      for (int c = 0; c < MIDC; ++c) {
        t0 += vv[c]*w2c[c].x; t1 += vv[c]*w2c[c].y;
        t2 += vv[c]*w2c[c].z; t3 += vv[c]*w2c[c].w;
      }
      pacc.x += fmaxf(t0, 0.f); pacc.y += fmaxf(t1, 0.f);
      pacc.z += fmaxf(t2, 0.f); pacc.w += fmaxf(t3, 0.f);
    }
    float4* part4 = (float4*)(sm + OFF_CSR);           // reuse CSR space: [16][256]
    part4[(ig << 6) + h4] = pacc;
  }
  __syncthreads();
  if (tid < HH) {
    const float* part = sm + OFF_CSR;
    float s = 0.f;
#pragma unroll
    for (int ig = 0; ig < 16; ++ig) s += part[ig*HH + tid];
    emb[(size_t)g*HH + tid] = s * (1.0f/(float)KK);
  }
}

// ---------------------------------------------------------------------------
// K2: A[g,j] = emb[g]@W_ih[j] + b_ih[j] + b_hh[j]; one block/graph, 1024 thr.
// Each row j handled by 16 lanes (coalesced 256 B chunks) + shfl reduce.
// ---------------------------------------------------------------------------
__global__ __launch_bounds__(1024) void k_gatepre(
    const float* __restrict__ emb, const float* __restrict__ W_ih,
    const float* __restrict__ b_ih, const float* __restrict__ b_hh,
    float* __restrict__ A)
{
  __shared__ __align__(16) float es[HH];
  const int g = blockIdx.x, tid = threadIdx.x;
  const int wid = tid >> 6, lane = tid & 63;
  const int sub = lane & 15, rq = lane >> 4;
  if (tid < HH) es[tid] = emb[(size_t)g*HH + tid];
  __syncthreads();
  const float4* e4 = (const float4*)es;
  for (int it = 0; it < 16; ++it) {
    const int j = it*64 + wid*4 + rq;
    const float4* wr = (const float4*)(W_ih + (size_t)j*HH);
    float p = 0.f;
#pragma unroll
    for (int kk = 0; kk < 4; ++kk) {
      float4 w = wr[sub + 16*kk];
      float4 e = e4[sub + 16*kk];
      p += w.x*e.x + w.y*e.y + w.z*e.z + w.w*e.w;
    }
    p += __shfl_xor(p, 1); p += __shfl_xor(p, 2);
    p += __shfl_xor(p, 4); p += __shfl_xor(p, 8);
    if (sub == 0) A[(size_t)g*1024 + j] = p + b_ih[j] + b_hh[j];
  }
}

// ---------------------------------------------------------------------------
// K3: one LSTM timestep. grid = 256 blocks: block = (batch b, unit-group ug).
// Block reads its 64 weight rows (64 KB, coalesced, L2-hot) + h_in[b,:],
// computes 16 units' gates, updates c (in place) and writes h_out[b, units].
// Correct row mapping: row j = gate*256 + unit  (PyTorch i,f,g,o order).
// ---------------------------------------------------------------------------
__global__ __launch_bounds__(256) void k_step(
    const float* __restrict__ A_t, const float* __restrict__ W_hh,
    const float* __restrict__ h_in, float* __restrict__ h_out,
    float* __restrict__ cbuf)
{
  __shared__ __align__(16) float hsh[HH];
  __shared__ float gl[16][4];
  const int b = blockIdx.x >> 4, ug = blockIdx.x & 15;
  const int tid = threadIdx.x;
  const int ul = tid >> 4, sub = tid & 15;
  if (tid < HH) hsh[tid] = h_in[b*HH + tid];
  __syncthreads();
  const float4* h4 = (const float4*)hsh;
  float4 hv0 = h4[sub], hv1 = h4[sub+16], hv2 = h4[sub+32], hv3 = h4[sub+48];
  const int u = ug*16 + ul;
  float gv[4];
#pragma unroll
  for (int gg_ = 0; gg_ < 4; ++gg_) {
    const float4* wr = (const float4*)(W_hh + (size_t)(gg_*HH + u)*HH);
    float4 w0 = wr[sub], w1 = wr[sub+16], w2 = wr[sub+32], w3 = wr[sub+48];
    float p = w0.x*hv0.x + w0.y*hv0.y + w0.z*hv0.z + w0.w*hv0.w
            + w1.x*hv1.x + w1.y*hv1.y + w1.z*hv1.z + w1.w*hv1.w
            + w2.x*hv2.x + w2.y*hv2.y + w2.z*hv2.z + w2.w*hv2.w
            + w3.x*hv3.x + w3.y*hv3.y + w3.z*hv3.z + w3.w*hv3.w;
    p += __shfl_xor(p, 1); p += __shfl_xor(p, 2);
    p += __shfl_xor(p, 4); p += __shfl_xor(p, 8);
    gv[gg_] = p;
  }
  if (sub == 0) { gl[ul][0]=gv[0]; gl[ul][1]=gv[1]; gl[ul][2]=gv[2]; gl[ul][3]=gv[3]; }
  __syncthreads();
  if (tid < 16) {
    const int uu = ug*16 + tid;
    const float* At = A_t + b*1024;
    float gi = gl[tid][0] + At[uu      ];
    float gf = gl[tid][1] + At[uu + 256];
    float gn = gl[tid][2] + At[uu + 512];
    float go = gl[tid][3] + At[uu + 768];
    float iv = 1.0f/(1.0f + expf(-gi));
    float fv = 1.0f/(1.0f + expf(-gf));
    float gvv = tanhf(gn);
    float ov = 1.0f/(1.0f + expf(-go));
    float c = fv * cbuf[b*HH + uu] + iv * gvv;
    cbuf[b*HH + uu] = c;
    h_out[b*HH + uu] = ov * tanhf(c);
  }
}

// ---------------------------------------------------------------------------
// K4: classifier out[b] = h[b,:]@cls_W + cls_b
// ---------------------------------------------------------------------------
__global__ __launch_bounds__(256) void k_cls(
    const float* __restrict__ h, const float* __restrict__ cls_W,
    const float* __restrict__ cls_b, float* __restrict__ out)
{
  __shared__ float red[4];
  const int b = blockIdx.x, tid = threadIdx.x;
  float p = h[b*HH + tid] * cls_W[tid];
#pragma unroll
  for (int off = 32; off >= 1; off >>= 1) p += __shfl_down(p, off);
  if ((tid & 63) == 0) red[tid >> 6] = p;
  __syncthreads();
  if (tid == 0) out[b] = red[0] + red[1] + red[2] + red[3] + cls_b[0];
}

// ---------------------------------------------------------------------------
extern "C" void kernel_launch(void* const* d_in, const int* in_sizes, int n_in,
                              void* d_out, int out_size, void* d_ws, size_t ws_size,
                              hipStream_t stream)
{
  const float* x    = (const float*)d_in[0];
  const int*   ei   = (const int*)  d_in[1];
  const float* W1   = (const float*)d_in[2];
  const float* b1   = (const float*)d_in[3];
  const float* Wl   = (const float*)d_in[4];
  const float* Wr   = (const float*)d_in[5];
  const float* bs   = (const float*)d_in[6];
  const float* W2   = (const float*)d_in[7];
  const float* b2   = (const float*)d_in[8];
  const float* Wih  = (const float*)d_in[9];
  const float* Whh  = (const float*)d_in[10];
  const float* bih  = (const float*)d_in[11];
  const float* bhh  = (const float*)d_in[12];
  const float* clsW = (const float*)d_in[13];
  const float* clsb = (const float*)d_in[14];
  float* out = (float*)d_out;

  float* emb = (float*)d_ws;                    // [T*B, 256]  (dead after k_gatepre)
  float* A   = emb + (size_t)TT*BB*HH;          // [T*B, 1024]
  // LSTM state buffers overlap the dead emb region (ws footprint unchanged)
  float* hA  = emb;                             // [16][256]
  float* hB  = emb + BB*HH;                     // [16][256]
  float* cb  = emb + 2*BB*HH;                   // [16][256]

  (void)hipFuncSetAttribute(reinterpret_cast<const void*>(k_graph),
      hipFuncAttributeMaxDynamicSharedMemorySize, SM_BYTES);

  hipLaunchKernelGGL(k_graph, dim3(TT*BB), dim3(1024), SM_BYTES, stream,
                     x, ei, W1, b1, Wl, Wr, bs, W2, b2, emb);
  hipLaunchKernelGGL(k_gatepre, dim3(TT*BB), dim3(1024), 0, stream,
                     emb, Wih, bih, bhh, A);
  (void)hipMemsetAsync(hA, 0, BB*HH*sizeof(float), stream);
  (void)hipMemsetAsync(cb, 0, BB*HH*sizeof(float), stream);
  for (int t = 0; t < TT; ++t) {
    const float* hin  = (t & 1) ? hB : hA;
    float*       hout = (t & 1) ? hA : hB;
    hipLaunchKernelGGL(k_step, dim3(256), dim3(256), 0, stream,
                       A + (size_t)t*BB*1024, Whh, hin, hout, cb);
  }
  // TT=16 (even) -> final h is in hA
  hipLaunchKernelGGL(k_cls, dim3(BB), dim3(256), 0, stream, hA, clsW, clsb, out);
}